// Round 12
// baseline (186.162 us; speedup 1.0000x reference)
//
#include <hip/hip_runtime.h>
#include <math.h>

// Problem constants (fixed by setup_inputs)
#define NN   256   // N rows
#define CCH  512   // C features
#define MMM  64    // M slices
#define KPOS 8     // K positives
#define MARG 0.2f

typedef _Float16 f16x8 __attribute__((ext_vector_type(8)));
typedef float    f32x4 __attribute__((ext_vector_type(4)));

// Packed fragment layout (MFMA A and B operands read the same pattern):
// P[m][rb][cb][lane] : lane l holds X[m][rb*16 + (l&15)][cb*32 + (l>>4)*8 + j]
#define FRAG(m, rb, cb) ((((size_t)(m) * 16 + (rb)) * 16 + (cb)) * 64)

// Workspace layout (bytes). Single fp16 copy (round-7: single-pass fp16 is
// exact-distances-of-rounded-points; error ~2e-4 << 2.1e-2 threshold).
#define PH_OFF   ((size_t)0)
#define PH_BYTES ((size_t)MMM * 16 * 16 * 64 * 16)   // 16,777,216
#define X2_OFF   (PH_OFF + PH_BYTES)
#define DAP_OFF  (X2_OFF + (size_t)MMM * NN * 4)
#define POS_OFF  (DAP_OFF + (size_t)MMM * NN * KPOS * 4)
#define NEG_OFF  (POS_OFF + (size_t)NN * KPOS * 4)
#define S_OFF    (NEG_OFF + (size_t)NN * 4 * 8)
#define CNT_OFF  (S_OFF + (size_t)MMM * 4)
#define DONE_OFF (CNT_OFF + (size_t)MMM * 4)
#define PRED_OFF (DONE_OFF + 64)

// async global->LDS, 16B per lane: LDS dest = wave-uniform base + lane*16
#define GLD_LDS16(gp, lp) __builtin_amdgcn_global_load_lds(                 \
    (const __attribute__((address_space(1))) void*)(gp),                    \
    (__attribute__((address_space(3))) void*)(lp), 16, 0, 0)

// ---------------------------------------------------------------------------
// Kernel TH: fused transpose + fp16 convert + fragment packing.
// Block 1024 runs the kP logic via ballots and zeroes accumulators+counters.
// ---------------------------------------------------------------------------
__global__ __launch_bounds__(256) void kTH(const float* __restrict__ f,
                                           f16x8* __restrict__ Ph,
                                           const int* __restrict__ label,
                                           int* __restrict__ pos_idx,
                                           unsigned long long* __restrict__ neg_mask,
                                           float* __restrict__ s_acc,
                                           unsigned int* __restrict__ c_acc,
                                           unsigned int* __restrict__ done,
                                           unsigned int* __restrict__ preDone) {
  __shared__ unsigned int S[512 * 20];   // 40 KB
  int bid = blockIdx.x;
  int t = threadIdx.x;

  if (bid >= 1024) {                     // ---- kP body (ballot version) ----
    unsigned long long* cm = (unsigned long long*)S;   // [32 classes][4 words]
    if (t < MMM) { s_acc[t] = 0.0f; c_acc[t] = 0u; }
    if (t == 0) { *done = 0u; *preDone = 0u; }
    int lab = label[t];                  // t == k, 256 threads == NN
    int wv = t >> 6;
    #pragma unroll 1
    for (int c = 0; c < 32; ++c) {
      unsigned long long b = __ballot(lab == c);
      if ((t & 63) == 0) cm[c * 4 + wv] = b;
    }
    __syncthreads();
    int n = t;
    unsigned long long pm0 = cm[lab*4+0], pm1 = cm[lab*4+1],
                       pm2 = cm[lab*4+2], pm3 = cm[lab*4+3];
    const unsigned long long P0 = pm0, P1 = pm1, P2 = pm2, P3 = pm3;
    unsigned long long e0 = 0, e1 = 0, e2 = 0, e3 = 0;
    #pragma unroll
    for (int r = 0; r < 8; ++r) {        // first 8 of stable order (pos then neg)
      unsigned long long q0 = pm0, q1 = pm1, q2 = pm2, q3 = pm3;
      if (!(pm0 | pm1 | pm2 | pm3)) {    // P<8 fallback: promote negatives
        q0 = ~(P0 | e0); q1 = ~(P1 | e1); q2 = ~(P2 | e2); q3 = ~(P3 | e3);
      }
      int k;
      if (q0) k = __builtin_ctzll(q0);
      else if (q1) k = 64 + __builtin_ctzll(q1);
      else if (q2) k = 128 + __builtin_ctzll(q2);
      else if (q3) k = 192 + __builtin_ctzll(q3);
      else k = 0;
      pos_idx[n * KPOS + r] = k;
      unsigned long long b = 1ull << (k & 63);
      if (k < 64)       { pm0 &= ~b; e0 |= b; }
      else if (k < 128) { pm1 &= ~b; e1 |= b; }
      else if (k < 192) { pm2 &= ~b; e2 |= b; }
      else              { pm3 &= ~b; e3 |= b; }
    }
    neg_mask[n*4+0] = ~e0; neg_mask[n*4+1] = ~e1;
    neg_mask[n*4+2] = ~e2; neg_mask[n*4+3] = ~e3;
    return;
  }

  int rb = bid >> 6, cb = (bid >> 2) & 15, mq = bid & 3;
  // read phase: 512 (n,c) pairs x 16 m; each thread: 8 float4 loads
  int s = t & 3, pg = t >> 2;
  #pragma unroll
  for (int it = 0; it < 8; ++it) {
    int p = it * 64 + pg;               // 0..511
    int n_loc = p & 15, c_loc = p >> 4;
    const float4 v4 = *(const float4*)&f[((size_t)(rb * 16 + n_loc) * CCH
                                          + (cb * 32 + c_loc)) * MMM + mq * 16 + s * 4];
    uint4 pk;
    pk.x = (unsigned int)__builtin_bit_cast(unsigned short, (_Float16)v4.x);
    pk.y = (unsigned int)__builtin_bit_cast(unsigned short, (_Float16)v4.y);
    pk.z = (unsigned int)__builtin_bit_cast(unsigned short, (_Float16)v4.z);
    pk.w = (unsigned int)__builtin_bit_cast(unsigned short, (_Float16)v4.w);
    *(uint4*)&S[p * 20 + s * 4] = pk;   // 16B-aligned
  }
  __syncthreads();
  // write phase: 16 m_loc x 64 lanes fragments, coalesced 16B stores
  #pragma unroll
  for (int it = 0; it < 4; ++it) {
    int e = it * 256 + t;
    int m_loc = e >> 6, l = e & 63;
    int m = mq * 16 + m_loc;
    f16x8 vh;
    #pragma unroll
    for (int j = 0; j < 8; ++j) {
      unsigned int w = S[(((l >> 4) * 8 + j) * 16 + (l & 15)) * 20 + m_loc];
      vh[j] = __builtin_bit_cast(_Float16, (unsigned short)(w & 0xffffu));
    }
    Ph[FRAG(m, rb, cb) + l] = vh;
  }
}

// ---------------------------------------------------------------------------
// Kernel BF (fused): [A2 prologue slices] -> device barrier -> [triangle-tiled
// Gram+loss (r9 structure, best measured)] -> done counter -> finalize.
// Rationale (r7-r10 data): kB internals are invariance-class; totals track
// DISPATCH COUNT (~10us/node). 3 nodes -> 2.
// Deadlock-safety: __launch_bounds__(256,3) => >=3 blocks/CU => capacity 768
// >= grid 640, so all blocks co-resident before anyone spins.
// ---------------------------------------------------------------------------
#define MFMA16(d, a, b) d = __builtin_amdgcn_mfma_f32_16x16x32_f16(a, b, d, 0, 0, 0)

__global__ __launch_bounds__(256, 3) void kBF(
    const f16x8* __restrict__ Ph, const int* __restrict__ pos_idx,
    float* __restrict__ x2, float* __restrict__ dap,
    const unsigned long long* __restrict__ neg_mask,
    float* __restrict__ s_acc, unsigned int* __restrict__ c_acc,
    unsigned int* __restrict__ done, unsigned int* __restrict__ preDone,
    float* __restrict__ out) {
  __shared__ __align__(16) char smem[17024];   // overlaid prologue/main LDS

  int bid = blockIdx.x;                 // 640 blocks
  int t = threadIdx.x, lane = t & 63, w = t >> 6;

  // ======== PROLOGUE: kA2 slices, grid-strided (3-4 per block) ========
  {
    float (*R)[520] = (float (*)[520])smem;          // 16640 B
    float* D8 = (float*)(smem + 16640);              // +256 B
    #pragma unroll 1
    for (int s = bid; s < 2048; s += 640) {
      int pm = s & 63, cl = s >> 6;
      #pragma unroll
      for (int half = 0; half < 2; ++half) {
        int e = half * 256 + t;
        int i = e >> 6, le = e & 63, cbb = le >> 2, g = le & 3;
        int mi = pos_idx[cl * 8 + i];
        f16x8 vh = Ph[FRAG(pm, mi >> 4, cbb) + (g * 16 + (mi & 15))];
        #pragma unroll
        for (int j = 0; j < 8; ++j)
          R[i][cbb * 32 + g * 8 + j] = (float)vh[j];
      }
      __syncthreads();
      {
        int d = t >> 2, q = t & 3, i = d >> 3, i2 = d & 7;
        const float4* Ri4 = (const float4*)(&R[i][q * 128]);
        const float4* Rj4 = (const float4*)(&R[i2][q * 128]);
        float p = 0.0f;
        #pragma unroll
        for (int c = 0; c < 32; ++c) {
          float4 a = Ri4[c], b = Rj4[c];
          p += a.x * b.x + a.y * b.y + a.z * b.z + a.w * b.w;
        }
        p += __shfl_down(p, 2, 4);
        p += __shfl_down(p, 1, 4);
        if (q == 0) D8[d] = p;
      }
      __syncthreads();
      if (t < 64) {
        int ii = t >> 3, jj = t & 7;
        float x2a = D8[ii * 8 + ii], x2b = D8[jj * 8 + jj];
        float z = x2a + x2b - 2.0f * D8[t];
        float dist = (z > 0.0f) ? sqrtf(z) : 0.0f;
        int mi = pos_idx[cl * 8 + ii];
        dap[((size_t)pm * NN + mi) * KPOS + jj] = dist;
        if (ii == jj) x2[pm * NN + mi] = x2a;
      }
      __syncthreads();                  // protect R/D8 reuse across slices
    }
  }
  __threadfence();                      // release dap/x2 device-wide
  if (t == 0) {
    atomicAdd(preDone, 1u);
    while (atomicAdd(preDone, 0u) < 640u) __builtin_amdgcn_s_sleep(8);
  }
  __syncthreads();
  __threadfence();                      // acquire other blocks' dap/x2

  // ======== MAIN: triangle-tiled Gram -> dist -> loss (r9 structure) ========
  char* Lds = smem;                     // [2][8192]
  float* red_s = (float*)(smem + 16384);
  unsigned int* red_c = (unsigned int*)(smem + 16400);
  unsigned int* lastFlag = (unsigned int*)(smem + 16416);

  int m = bid & 63;                     // XCD-aligned: m%8 == bid%8
  int sub = bid >> 6;                   // 0..9 triangle tile id
  int ti, tj;
  if (sub < 4) { ti = sub; tj = sub; }
  else {
    int u = sub - 4;                    // (0,1)(0,2)(0,3)(1,2)(1,3)(2,3)
    ti = (u < 3) ? 0 : ((u < 5) ? 1 : 2);
    tj = (u < 3) ? (u + 1) : ((u < 5) ? (u - 2) : 3);
  }
  const bool diag = (ti == tj);
  int wr = w & 1, wc = w >> 1;          // wave: 32k x 32n sub-tile

  f32x4 hh[2][2];
  #pragma unroll
  for (int i = 0; i < 2; ++i)
    #pragma unroll
    for (int j = 0; j < 2; ++j) hh[i][j] = (f32x4){0.f, 0.f, 0.f, 0.f};

  // off-diag: 8 frag-blocks (b<4: A rows ti, b>=4: B rows tj); diag: 4 (A only)
  #define STAGE(nbuf, cbn)                                                   \
    if (diag) {                                                              \
      GLD_LDS16(Ph + FRAG(m, ti * 4 + w, (cbn)) + lane,                      \
                Lds + (nbuf) * 8192 + w * 1024);                             \
    } else {                                                                 \
      { int b = w * 2;     int rbg = (b < 4) ? (ti*4 + b) : (tj*4 + b - 4);  \
        GLD_LDS16(Ph + FRAG(m, rbg, (cbn)) + lane,                           \
                  Lds + (nbuf) * 8192 + b * 1024); }                         \
      { int b = w * 2 + 1; int rbg = (b < 4) ? (ti*4 + b) : (tj*4 + b - 4);  \
        GLD_LDS16(Ph + FRAG(m, rbg, (cbn)) + lane,                           \
                  Lds + (nbuf) * 8192 + b * 1024); }                         \
    }

  STAGE(0, 0);
  __syncthreads();
  #pragma unroll 1
  for (int cb = 0; cb < 16; ++cb) {
    int buf = cb & 1;
    if (cb < 15) STAGE(buf ^ 1, cb + 1);
    __builtin_amdgcn_sched_barrier(0);  // pin stage-issue before compute
    const f16x8* L  = (const f16x8*)(Lds + buf * 8192);
    const f16x8* LB = diag ? L : (L + 4 * 64);
    f16x8 ah0 = L [(wr * 2 + 0) * 64 + lane];
    f16x8 ah1 = L [(wr * 2 + 1) * 64 + lane];
    f16x8 bh0 = LB[(wc * 2 + 0) * 64 + lane];
    f16x8 bh1 = LB[(wc * 2 + 1) * 64 + lane];
    MFMA16(hh[0][0], ah0, bh0); MFMA16(hh[0][1], ah0, bh1);
    MFMA16(hh[1][0], ah1, bh0); MFMA16(hh[1][1], ah1, bh1);
    __syncthreads();                    // drains vmcnt(0): buf^1 staged
  }

  // Epilogue. D frag: col = lane&15 (n side), row = (lane>>4)*4 + reg (k side).
  int col = lane & 15, rq = lane >> 4;
  int n0 = tj * 64 + wc * 32 + col;
  int n1 = n0 + 16;
  float x2n0 = x2[m * NN + n0], x2n1 = x2[m * NN + n1];
  float dv0[8], dv1[8];
  {
    const float4* dp0 = (const float4*)&dap[((size_t)m * NN + n0) * KPOS];
    const float4* dp1 = (const float4*)&dap[((size_t)m * NN + n1) * KPOS];
    float4 w0 = dp0[0], w1 = dp0[1], w2 = dp1[0], w3 = dp1[1];
    dv0[0]=w0.x; dv0[1]=w0.y; dv0[2]=w0.z; dv0[3]=w0.w;
    dv0[4]=w1.x; dv0[5]=w1.y; dv0[6]=w1.z; dv0[7]=w1.w;
    dv1[0]=w2.x; dv1[1]=w2.y; dv1[2]=w2.z; dv1[3]=w2.w;
    dv1[4]=w3.x; dv1[5]=w3.y; dv1[6]=w3.z; dv1[7]=w3.w;
  }
  unsigned long long nmw0 = neg_mask[n0 * 4 + ti];   // k word == ti
  unsigned long long nmw1 = neg_mask[n1 * 4 + ti];

  float ls = 0.0f; unsigned int lc = 0u;
  #pragma unroll
  for (int i = 0; i < 2; ++i) {
    #pragma unroll
    for (int reg = 0; reg < 4; ++reg) {
      int klo = wr * 32 + i * 16 + rq * 4 + reg;     // k & 63
      int k = ti * 64 + klo;
      float x2k = x2[m * NN + k];
      float z0 = x2n0 + x2k - 2.0f * hh[i][0][reg];
      float d0 = (z0 > 0.0f) ? sqrtf(z0) : 0.0f;
      float z1 = x2n1 + x2k - 2.0f * hh[i][1][reg];
      float d1 = (z1 > 0.0f) ? sqrtf(z1) : 0.0f;
      // orientation 1: n = cols (n0/n1), k = row
      if ((nmw0 >> klo) & 1ull) {
        #pragma unroll
        for (int p = 0; p < 8; ++p) {
          float tt = MARG + dv0[p] - d0;
          if (tt > 0.0f) { ls += tt; lc++; }
        }
      }
      if ((nmw1 >> klo) & 1ull) {
        #pragma unroll
        for (int p = 0; p < 8; ++p) {
          float tt = MARG + dv1[p] - d1;
          if (tt > 0.0f) { ls += tt; lc++; }
        }
      }
      // orientation 2 (off-diag only): n = row k, negatives = cols n0/n1
      if (!diag) {
        const float4* dpr = (const float4*)&dap[((size_t)m * NN + k) * KPOS];
        float4 q0 = dpr[0], q1 = dpr[1];
        unsigned long long nmr = neg_mask[k * 4 + tj];
        int bit0 = wc * 32 + col;
        if ((nmr >> bit0) & 1ull) {
          float tt;
          tt = MARG + q0.x - d0; if (tt > 0.0f) { ls += tt; lc++; }
          tt = MARG + q0.y - d0; if (tt > 0.0f) { ls += tt; lc++; }
          tt = MARG + q0.z - d0; if (tt > 0.0f) { ls += tt; lc++; }
          tt = MARG + q0.w - d0; if (tt > 0.0f) { ls += tt; lc++; }
          tt = MARG + q1.x - d0; if (tt > 0.0f) { ls += tt; lc++; }
          tt = MARG + q1.y - d0; if (tt > 0.0f) { ls += tt; lc++; }
          tt = MARG + q1.z - d0; if (tt > 0.0f) { ls += tt; lc++; }
          tt = MARG + q1.w - d0; if (tt > 0.0f) { ls += tt; lc++; }
        }
        if ((nmr >> (bit0 + 16)) & 1ull) {
          float tt;
          tt = MARG + q0.x - d1; if (tt > 0.0f) { ls += tt; lc++; }
          tt = MARG + q0.y - d1; if (tt > 0.0f) { ls += tt; lc++; }
          tt = MARG + q0.z - d1; if (tt > 0.0f) { ls += tt; lc++; }
          tt = MARG + q0.w - d1; if (tt > 0.0f) { ls += tt; lc++; }
          tt = MARG + q1.x - d1; if (tt > 0.0f) { ls += tt; lc++; }
          tt = MARG + q1.y - d1; if (tt > 0.0f) { ls += tt; lc++; }
          tt = MARG + q1.z - d1; if (tt > 0.0f) { ls += tt; lc++; }
          tt = MARG + q1.w - d1; if (tt > 0.0f) { ls += tt; lc++; }
        }
      }
    }
  }
  #pragma unroll
  for (int off = 32; off > 0; off >>= 1) {
    ls += __shfl_down(ls, off, 64);
    lc += __shfl_down(lc, off, 64);
  }
  if (lane == 0) { red_s[w] = ls; red_c[w] = lc; }
  __syncthreads();
  if (t == 0) {
    atomicAdd(&s_acc[m], red_s[0] + red_s[1] + red_s[2] + red_s[3]);
    atomicAdd(&c_acc[m], red_c[0] + red_c[1] + red_c[2] + red_c[3]);
    __threadfence();
    unsigned int prev = atomicAdd(done, 1u);
    *lastFlag = (prev == 639u) ? 1u : 0u;
  }
  __syncthreads();
  if (*lastFlag && t < 64) {            // last block finalizes (fold of kC)
    __threadfence();
    float c  = (float)c_acc[t];
    float sm = s_acc[t];
    float mean = (c > 0.0f) ? (sm / c) : 0.0f;
    float csum = c;
    #pragma unroll
    for (int off = 32; off > 0; off >>= 1) {
      mean += __shfl_down(mean, off, 64);
      csum += __shfl_down(csum, off, 64);
    }
    if (t == 0) {
      out[0] = mean / 64.0f;
      // lm.size = M * N * K * (N-K) = 64*256*8*248 = 32,505,856
      out[1] = (csum / 64.0f) / 32505856.0f;
    }
  }
}

extern "C" void kernel_launch(void* const* d_in, const int* in_sizes, int n_in,
                              void* d_out, int out_size, void* d_ws, size_t ws_size,
                              hipStream_t stream) {
  const float* feature = (const float*)d_in[0];
  const int*   label   = (const int*)d_in[1];
  char* w = (char*)d_ws;
  f16x8* Ph = (f16x8*)(w + PH_OFF);
  float* x2  = (float*)(w + X2_OFF);
  float* dap = (float*)(w + DAP_OFF);
  int*   pos = (int*)(w + POS_OFF);
  unsigned long long* neg = (unsigned long long*)(w + NEG_OFF);
  float* s_acc = (float*)(w + S_OFF);
  unsigned int* c_acc = (unsigned int*)(w + CNT_OFF);
  unsigned int* done  = (unsigned int*)(w + DONE_OFF);
  unsigned int* preD  = (unsigned int*)(w + PRED_OFF);
  float* out = (float*)d_out;

  kTH<<<1025, 256, 0, stream>>>(feature, Ph, label, pos, neg, s_acc, c_acc, done, preD);
  kBF<<<640,  256, 0, stream>>>(Ph, pos, x2, dap, neg, s_acc, c_acc, done, preD, out);
}

// Round 13
// 59.539 us; speedup vs baseline: 3.1267x; 3.1267x over previous
//
#include <hip/hip_runtime.h>
#include <math.h>

// Problem constants (fixed by setup_inputs)
#define NN   256   // N rows
#define CCH  512   // C features
#define MMM  64    // M slices
#define KPOS 8     // K positives
#define MARG 0.2f

typedef _Float16 f16x8 __attribute__((ext_vector_type(8)));
typedef float    f32x4 __attribute__((ext_vector_type(4)));

// Packed fragment layout (MFMA A and B operands read the same pattern):
// P[m][rb][cb][lane] : lane l holds X[m][rb*16 + (l&15)][cb*32 + (l>>4)*8 + j]
#define FRAG(m, rb, cb) ((((size_t)(m) * 16 + (rb)) * 16 + (cb)) * 64)

// Workspace layout (bytes). Single fp16 copy (round-7: single-pass fp16 is
// exact-distances-of-rounded-points; error ~2e-4 << 2.1e-2 threshold).
#define PH_OFF   ((size_t)0)
#define PH_BYTES ((size_t)MMM * 16 * 16 * 64 * 16)   // 16,777,216
#define X2_OFF   (PH_OFF + PH_BYTES)
#define DAP_OFF  (X2_OFF + (size_t)MMM * NN * 4)
#define POS_OFF  (DAP_OFF + (size_t)MMM * NN * KPOS * 4)
#define NEG_OFF  (POS_OFF + (size_t)NN * KPOS * 4)
#define S_OFF    (NEG_OFF + (size_t)NN * 4 * 8)
#define CNT_OFF  (S_OFF + (size_t)MMM * 4)
#define DONE_OFF (CNT_OFF + (size_t)MMM * 4)

// async global->LDS, 16B per lane: LDS dest = wave-uniform base + lane*16
#define GLD_LDS16(gp, lp) __builtin_amdgcn_global_load_lds(                 \
    (const __attribute__((address_space(1))) void*)(gp),                    \
    (__attribute__((address_space(3))) void*)(lp), 16, 0, 0)

// ---------------------------------------------------------------------------
// Kernel TH: fused transpose + fp16 convert + fragment packing.
// Block 1024 runs the kP logic via ballots and zeroes accumulators + done.
// ---------------------------------------------------------------------------
__global__ __launch_bounds__(256) void kTH(const float* __restrict__ f,
                                           f16x8* __restrict__ Ph,
                                           const int* __restrict__ label,
                                           int* __restrict__ pos_idx,
                                           unsigned long long* __restrict__ neg_mask,
                                           float* __restrict__ s_acc,
                                           unsigned int* __restrict__ c_acc,
                                           unsigned int* __restrict__ done) {
  __shared__ unsigned int S[512 * 20];   // 40 KB
  int bid = blockIdx.x;
  int t = threadIdx.x;

  if (bid >= 1024) {                     // ---- kP body (ballot version) ----
    unsigned long long* cm = (unsigned long long*)S;   // [32 classes][4 words]
    if (t < MMM) { s_acc[t] = 0.0f; c_acc[t] = 0u; }
    if (t == 0) *done = 0u;
    int lab = label[t];                  // t == k, 256 threads == NN
    int wv = t >> 6;
    #pragma unroll 1
    for (int c = 0; c < 32; ++c) {
      unsigned long long b = __ballot(lab == c);
      if ((t & 63) == 0) cm[c * 4 + wv] = b;
    }
    __syncthreads();
    int n = t;
    unsigned long long pm0 = cm[lab*4+0], pm1 = cm[lab*4+1],
                       pm2 = cm[lab*4+2], pm3 = cm[lab*4+3];
    const unsigned long long P0 = pm0, P1 = pm1, P2 = pm2, P3 = pm3;
    unsigned long long e0 = 0, e1 = 0, e2 = 0, e3 = 0;
    #pragma unroll
    for (int r = 0; r < 8; ++r) {        // first 8 of stable order (pos then neg)
      unsigned long long q0 = pm0, q1 = pm1, q2 = pm2, q3 = pm3;
      if (!(pm0 | pm1 | pm2 | pm3)) {    // P<8 fallback: promote negatives
        q0 = ~(P0 | e0); q1 = ~(P1 | e1); q2 = ~(P2 | e2); q3 = ~(P3 | e3);
      }
      int k;
      if (q0) k = __builtin_ctzll(q0);
      else if (q1) k = 64 + __builtin_ctzll(q1);
      else if (q2) k = 128 + __builtin_ctzll(q2);
      else if (q3) k = 192 + __builtin_ctzll(q3);
      else k = 0;
      pos_idx[n * KPOS + r] = k;
      unsigned long long b = 1ull << (k & 63);
      if (k < 64)       { pm0 &= ~b; e0 |= b; }
      else if (k < 128) { pm1 &= ~b; e1 |= b; }
      else if (k < 192) { pm2 &= ~b; e2 |= b; }
      else              { pm3 &= ~b; e3 |= b; }
    }
    neg_mask[n*4+0] = ~e0; neg_mask[n*4+1] = ~e1;
    neg_mask[n*4+2] = ~e2; neg_mask[n*4+3] = ~e3;
    return;
  }

  int rb = bid >> 6, cb = (bid >> 2) & 15, mq = bid & 3;
  // read phase: 512 (n,c) pairs x 16 m; each thread: 8 float4 loads
  int s = t & 3, pg = t >> 2;
  #pragma unroll
  for (int it = 0; it < 8; ++it) {
    int p = it * 64 + pg;               // 0..511
    int n_loc = p & 15, c_loc = p >> 4;
    const float4 v4 = *(const float4*)&f[((size_t)(rb * 16 + n_loc) * CCH
                                          + (cb * 32 + c_loc)) * MMM + mq * 16 + s * 4];
    uint4 pk;
    pk.x = (unsigned int)__builtin_bit_cast(unsigned short, (_Float16)v4.x);
    pk.y = (unsigned int)__builtin_bit_cast(unsigned short, (_Float16)v4.y);
    pk.z = (unsigned int)__builtin_bit_cast(unsigned short, (_Float16)v4.z);
    pk.w = (unsigned int)__builtin_bit_cast(unsigned short, (_Float16)v4.w);
    *(uint4*)&S[p * 20 + s * 4] = pk;   // 16B-aligned
  }
  __syncthreads();
  // write phase: 16 m_loc x 64 lanes fragments, coalesced 16B stores
  #pragma unroll
  for (int it = 0; it < 4; ++it) {
    int e = it * 256 + t;
    int m_loc = e >> 6, l = e & 63;
    int m = mq * 16 + m_loc;
    f16x8 vh;
    #pragma unroll
    for (int j = 0; j < 8; ++j) {
      unsigned int w = S[(((l >> 4) * 8 + j) * 16 + (l & 15)) * 20 + m_loc];
      vh[j] = __builtin_bit_cast(_Float16, (unsigned short)(w & 0xffffu));
    }
    Ph[FRAG(m, rb, cb) + l] = vh;
  }
}

// ---------------------------------------------------------------------------
// Kernel A2: per (m, class) 8x8 exact distances of the ROUNDED points.
// Self-distance exactly 0 structurally (diag uses the same D8 value twice).
// ---------------------------------------------------------------------------
__global__ __launch_bounds__(256) void kA2(const f16x8* __restrict__ Ph,
                                           const int* __restrict__ pos_idx,
                                           float* __restrict__ x2,
                                           float* __restrict__ dap) {
  __shared__ float R[8][520];
  __shared__ float D8[64];
  int bid = blockIdx.x;
  int m = bid & 63, cl = bid >> 6;
  int t = threadIdx.x;
  #pragma unroll
  for (int half = 0; half < 2; ++half) {
    int e = half * 256 + t;
    int i = e >> 6, le = e & 63, cbb = le >> 2, g = le & 3;
    int mi = pos_idx[cl * 8 + i];
    f16x8 vh = Ph[FRAG(m, mi >> 4, cbb) + (g * 16 + (mi & 15))];
    #pragma unroll
    for (int j = 0; j < 8; ++j)
      R[i][cbb * 32 + g * 8 + j] = (float)vh[j];
  }
  __syncthreads();
  {
    int d = t >> 2, q = t & 3, i = d >> 3, i2 = d & 7;
    const float4* Ri4 = (const float4*)(&R[i][q * 128]);
    const float4* Rj4 = (const float4*)(&R[i2][q * 128]);
    float p = 0.0f;
    #pragma unroll
    for (int c = 0; c < 32; ++c) {
      float4 a = Ri4[c], b = Rj4[c];
      p += a.x * b.x + a.y * b.y + a.z * b.z + a.w * b.w;
    }
    p += __shfl_down(p, 2, 4);
    p += __shfl_down(p, 1, 4);
    if (q == 0) D8[d] = p;
  }
  __syncthreads();
  if (t < 64) {
    int ii = t >> 3, jj = t & 7;
    float x2a = D8[ii * 8 + ii], x2b = D8[jj * 8 + jj];
    float z = x2a + x2b - 2.0f * D8[t];
    float dist = (z > 0.0f) ? sqrtf(z) : 0.0f;
    int mi = pos_idx[cl * 8 + ii];
    dap[((size_t)m * NN + mi) * KPOS + jj] = dist;
    if (ii == jj) x2[m * NN + mi] = x2a;
  }
}

// ---------------------------------------------------------------------------
// Kernel B v6: r9 triangle structure + COUNTED-vmcnt pipeline (guide T4).
// r5-r9 bug found: __syncthreads drains vmcnt(0), killing the same-iteration
// prefetch -> fully serial stage->compute. Now: 3 LDS buffers, depth-2
// prefetch, raw s_barrier + vmcnt(4) (peeled tail 2/0) -> loads stay in
// flight across barriers. Diag tiles duplicate A into the B slots so every
// block/chunk is uniformly 2 loads/wave (one vmcnt count for all).
// ---------------------------------------------------------------------------
#define MFMA16(d, a, b) d = __builtin_amdgcn_mfma_f32_16x16x32_f16(a, b, d, 0, 0, 0)

__global__ __launch_bounds__(256) void kB(
    const f16x8* __restrict__ Ph,
    const float* __restrict__ x2, const float* __restrict__ dap,
    const unsigned long long* __restrict__ neg_mask,
    float* __restrict__ s_acc, unsigned int* __restrict__ c_acc,
    unsigned int* __restrict__ done, float* __restrict__ out) {
  __shared__ __align__(16) char Lds[3][8 * 1024];   // 3-deep, 24 KB
  __shared__ float red_s[4];
  __shared__ unsigned int red_c[4];
  __shared__ unsigned int lastFlag;

  int bid = blockIdx.x;                 // 640 blocks
  int m = bid & 63;                     // XCD-aligned: m%8 == bid%8
  int sub = bid >> 6;                   // 0..9 triangle tile id
  int ti, tj;                           // A-side (rows/k) block, B-side (cols/n)
  if (sub < 4) { ti = sub; tj = sub; }
  else {
    int u = sub - 4;                    // (0,1)(0,2)(0,3)(1,2)(1,3)(2,3)
    ti = (u < 3) ? 0 : ((u < 5) ? 1 : 2);
    tj = (u < 3) ? (u + 1) : ((u < 5) ? (u - 2) : 3);
  }
  const bool diag = (ti == tj);
  int t = threadIdx.x, lane = t & 63, w = t >> 6;
  int wr = w & 1, wc = w >> 1;          // wave: 32k x 32n sub-tile

  f32x4 hh[2][2];
  #pragma unroll
  for (int i = 0; i < 2; ++i)
    #pragma unroll
    for (int j = 0; j < 2; ++j) hh[i][j] = (f32x4){0.f, 0.f, 0.f, 0.f};

  // uniform 8 frag-blocks/chunk: b<4 A rows (ti), b>=4 B rows (tj).
  // (diag: tj==ti -> A duplicated into B slots; keeps load count uniform.)
  #define STAGE(nbuf, cbn)                                                   \
    { { int b = w * 2;     int rbg = (b < 4) ? (ti*4 + b) : (tj*4 + b - 4);  \
        GLD_LDS16(Ph + FRAG(m, rbg, (cbn)) + lane, &Lds[nbuf][b * 1024]); }  \
      { int b = w * 2 + 1; int rbg = (b < 4) ? (ti*4 + b) : (tj*4 + b - 4);  \
        GLD_LDS16(Ph + FRAG(m, rbg, (cbn)) + lane, &Lds[nbuf][b * 1024]); } }

  STAGE(0, 0);
  STAGE(1, 1);
  #pragma unroll 1
  for (int cb = 0; cb < 16; ++cb) {
    int buf = cb % 3;
    // counted vmcnt (T4): own stage(cb) retired; other waves' via barrier.
    if (cb < 14) {
      STAGE((cb + 2) % 3, cb + 2);
      asm volatile("s_waitcnt vmcnt(4)" ::: "memory");   // {cb+1,cb+2} in flight
    } else if (cb == 14) {
      asm volatile("s_waitcnt vmcnt(2)" ::: "memory");   // {15} in flight
    } else {
      asm volatile("s_waitcnt vmcnt(0)" ::: "memory");
    }
    __builtin_amdgcn_s_barrier();       // raw barrier: no vmcnt drain
    __builtin_amdgcn_sched_barrier(0);  // pin reads below the barrier
    const f16x8* L  = (const f16x8*)(Lds[buf]);
    const f16x8* LB = L + 4 * 64;
    f16x8 ah0 = L [(wr * 2 + 0) * 64 + lane];
    f16x8 ah1 = L [(wr * 2 + 1) * 64 + lane];
    f16x8 bh0 = LB[(wc * 2 + 0) * 64 + lane];
    f16x8 bh1 = LB[(wc * 2 + 1) * 64 + lane];
    MFMA16(hh[0][0], ah0, bh0); MFMA16(hh[0][1], ah0, bh1);
    MFMA16(hh[1][0], ah1, bh0); MFMA16(hh[1][1], ah1, bh1);
  }

  // Epilogue. D frag: col = lane&15 (n side), row = (lane>>4)*4 + reg (k side).
  int col = lane & 15, rq = lane >> 4;
  int n0 = tj * 64 + wc * 32 + col;
  int n1 = n0 + 16;
  float x2n0 = x2[m * NN + n0], x2n1 = x2[m * NN + n1];
  float dv0[8], dv1[8];
  {
    const float4* dp0 = (const float4*)&dap[((size_t)m * NN + n0) * KPOS];
    const float4* dp1 = (const float4*)&dap[((size_t)m * NN + n1) * KPOS];
    float4 w0 = dp0[0], w1 = dp0[1], w2 = dp1[0], w3 = dp1[1];
    dv0[0]=w0.x; dv0[1]=w0.y; dv0[2]=w0.z; dv0[3]=w0.w;
    dv0[4]=w1.x; dv0[5]=w1.y; dv0[6]=w1.z; dv0[7]=w1.w;
    dv1[0]=w2.x; dv1[1]=w2.y; dv1[2]=w2.z; dv1[3]=w2.w;
    dv1[4]=w3.x; dv1[5]=w3.y; dv1[6]=w3.z; dv1[7]=w3.w;
  }
  unsigned long long nmw0 = neg_mask[n0 * 4 + ti];   // k word == ti
  unsigned long long nmw1 = neg_mask[n1 * 4 + ti];

  float ls = 0.0f; unsigned int lc = 0u;
  #pragma unroll
  for (int i = 0; i < 2; ++i) {
    #pragma unroll
    for (int reg = 0; reg < 4; ++reg) {
      int klo = wr * 32 + i * 16 + rq * 4 + reg;     // k & 63
      int k = ti * 64 + klo;
      float x2k = x2[m * NN + k];
      float z0 = x2n0 + x2k - 2.0f * hh[i][0][reg];
      float d0 = (z0 > 0.0f) ? sqrtf(z0) : 0.0f;
      float z1 = x2n1 + x2k - 2.0f * hh[i][1][reg];
      float d1 = (z1 > 0.0f) ? sqrtf(z1) : 0.0f;
      // orientation 1: n = cols (n0/n1), k = row
      if ((nmw0 >> klo) & 1ull) {
        #pragma unroll
        for (int p = 0; p < 8; ++p) {
          float tt = MARG + dv0[p] - d0;
          if (tt > 0.0f) { ls += tt; lc++; }
        }
      }
      if ((nmw1 >> klo) & 1ull) {
        #pragma unroll
        for (int p = 0; p < 8; ++p) {
          float tt = MARG + dv1[p] - d1;
          if (tt > 0.0f) { ls += tt; lc++; }
        }
      }
      // orientation 2 (off-diag only): n = row k, negatives = cols n0/n1
      if (!diag) {
        const float4* dpr = (const float4*)&dap[((size_t)m * NN + k) * KPOS];
        float4 q0 = dpr[0], q1 = dpr[1];
        unsigned long long nmr = neg_mask[k * 4 + tj];
        int bit0 = wc * 32 + col;
        if ((nmr >> bit0) & 1ull) {
          float tt;
          tt = MARG + q0.x - d0; if (tt > 0.0f) { ls += tt; lc++; }
          tt = MARG + q0.y - d0; if (tt > 0.0f) { ls += tt; lc++; }
          tt = MARG + q0.z - d0; if (tt > 0.0f) { ls += tt; lc++; }
          tt = MARG + q0.w - d0; if (tt > 0.0f) { ls += tt; lc++; }
          tt = MARG + q1.x - d0; if (tt > 0.0f) { ls += tt; lc++; }
          tt = MARG + q1.y - d0; if (tt > 0.0f) { ls += tt; lc++; }
          tt = MARG + q1.z - d0; if (tt > 0.0f) { ls += tt; lc++; }
          tt = MARG + q1.w - d0; if (tt > 0.0f) { ls += tt; lc++; }
        }
        if ((nmr >> (bit0 + 16)) & 1ull) {
          float tt;
          tt = MARG + q0.x - d1; if (tt > 0.0f) { ls += tt; lc++; }
          tt = MARG + q0.y - d1; if (tt > 0.0f) { ls += tt; lc++; }
          tt = MARG + q0.z - d1; if (tt > 0.0f) { ls += tt; lc++; }
          tt = MARG + q0.w - d1; if (tt > 0.0f) { ls += tt; lc++; }
          tt = MARG + q1.x - d1; if (tt > 0.0f) { ls += tt; lc++; }
          tt = MARG + q1.y - d1; if (tt > 0.0f) { ls += tt; lc++; }
          tt = MARG + q1.z - d1; if (tt > 0.0f) { ls += tt; lc++; }
          tt = MARG + q1.w - d1; if (tt > 0.0f) { ls += tt; lc++; }
        }
      }
    }
  }
  #pragma unroll
  for (int off = 32; off > 0; off >>= 1) {
    ls += __shfl_down(ls, off, 64);
    lc += __shfl_down(lc, off, 64);
  }
  if (lane == 0) { red_s[w] = ls; red_c[w] = lc; }
  __syncthreads();
  if (t == 0) {
    atomicAdd(&s_acc[m], red_s[0] + red_s[1] + red_s[2] + red_s[3]);
    atomicAdd(&c_acc[m], red_c[0] + red_c[1] + red_c[2] + red_c[3]);
    __threadfence();
    unsigned int prev = atomicAdd(done, 1u);
    lastFlag = (prev == 639u) ? 1u : 0u;
  }
  __syncthreads();
  if (lastFlag && t < 64) {             // last block finalizes (fold of kC)
    __threadfence();
    float c  = (float)c_acc[t];
    float sm = s_acc[t];
    float mean = (c > 0.0f) ? (sm / c) : 0.0f;
    float csum = c;
    #pragma unroll
    for (int off = 32; off > 0; off >>= 1) {
      mean += __shfl_down(mean, off, 64);
      csum += __shfl_down(csum, off, 64);
    }
    if (t == 0) {
      out[0] = mean / 64.0f;
      // lm.size = M * N * K * (N-K) = 64*256*8*248 = 32,505,856
      out[1] = (csum / 64.0f) / 32505856.0f;
    }
  }
}

extern "C" void kernel_launch(void* const* d_in, const int* in_sizes, int n_in,
                              void* d_out, int out_size, void* d_ws, size_t ws_size,
                              hipStream_t stream) {
  const float* feature = (const float*)d_in[0];
  const int*   label   = (const int*)d_in[1];
  char* w = (char*)d_ws;
  f16x8* Ph = (f16x8*)(w + PH_OFF);
  float* x2  = (float*)(w + X2_OFF);
  float* dap = (float*)(w + DAP_OFF);
  int*   pos = (int*)(w + POS_OFF);
  unsigned long long* neg = (unsigned long long*)(w + NEG_OFF);
  float* s_acc = (float*)(w + S_OFF);
  unsigned int* c_acc = (unsigned int*)(w + CNT_OFF);
  unsigned int* done  = (unsigned int*)(w + DONE_OFF);
  float* out = (float*)d_out;

  kTH<<<1025, 256, 0, stream>>>(feature, Ph, label, pos, neg, s_acc, c_acc, done);
  kA2<<<2048, 256, 0, stream>>>(Ph, pos, x2, dap);
  kB <<<640,  256, 0, stream>>>(Ph, x2, dap, neg, s_acc, c_acc, done, out);
}

// Round 14
// 59.070 us; speedup vs baseline: 3.1515x; 1.0079x over previous
//
#include <hip/hip_runtime.h>
#include <math.h>

// Problem constants (fixed by setup_inputs)
#define NN   256   // N rows
#define CCH  512   // C features
#define MMM  64    // M slices
#define KPOS 8     // K positives
#define MARG 0.2f

typedef _Float16 f16x8 __attribute__((ext_vector_type(8)));
typedef float    f32x4 __attribute__((ext_vector_type(4)));

// Packed fragment layout (MFMA A and B operands read the same pattern):
// P[m][rb][cb][lane] : lane l holds X[m][rb*16 + (l&15)][cb*32 + (l>>4)*8 + j]
#define FRAG(m, rb, cb) ((((size_t)(m) * 16 + (rb)) * 16 + (cb)) * 64)

// Workspace layout (bytes). Single fp16 copy (round-7: single-pass fp16 is
// exact-distances-of-rounded-points; error ~2e-4 << 2.1e-2 threshold).
#define PH_OFF   ((size_t)0)
#define PH_BYTES ((size_t)MMM * 16 * 16 * 64 * 16)   // 16,777,216
#define X2_OFF   (PH_OFF + PH_BYTES)
#define DAP_OFF  (X2_OFF + (size_t)MMM * NN * 4)
#define POS_OFF  (DAP_OFF + (size_t)MMM * NN * KPOS * 4)
#define NEG_OFF  (POS_OFF + (size_t)NN * KPOS * 4)
#define S_OFF    (NEG_OFF + (size_t)NN * 4 * 8)
#define CNT_OFF  (S_OFF + (size_t)MMM * 4)
#define DONE_OFF (CNT_OFF + (size_t)MMM * 4)

// async global->LDS, 16B per lane: LDS dest = wave-uniform base + lane*16
#define GLD_LDS16(gp, lp) __builtin_amdgcn_global_load_lds(                 \
    (const __attribute__((address_space(1))) void*)(gp),                    \
    (__attribute__((address_space(3))) void*)(lp), 16, 0, 0)

// ---------------------------------------------------------------------------
// Kernel TH: fused transpose + fp16 convert + fragment packing.
// Block 1024 runs the kP logic via ballots and zeroes accumulators + done.
// LDS layout r13: stride 17 words + XOR column (m ^ 4*(c_loc>>3)) on both
// sides. Old *20 layout was 8-way bank conflicted on reads (1.05M conflict
// cycles measured r6): both the x16 row coeff (320=10*32) and the lane-group
// coeff (2560=80*32) were = 0 mod 32. With 17: 17*li spans 16 distinct banks
// (gcd(17,32)=1) and the XOR breaks the lane-group degeneracy.
// ---------------------------------------------------------------------------
__global__ __launch_bounds__(256) void kTH(const float* __restrict__ f,
                                           f16x8* __restrict__ Ph,
                                           const int* __restrict__ label,
                                           int* __restrict__ pos_idx,
                                           unsigned long long* __restrict__ neg_mask,
                                           float* __restrict__ s_acc,
                                           unsigned int* __restrict__ c_acc,
                                           unsigned int* __restrict__ done) {
  __shared__ unsigned int S[512 * 17 + 16];   // ~34.9 KB
  int bid = blockIdx.x;
  int t = threadIdx.x;

  if (bid >= 1024) {                     // ---- kP body (ballot version) ----
    unsigned long long* cm = (unsigned long long*)S;   // [32 classes][4 words]
    if (t < MMM) { s_acc[t] = 0.0f; c_acc[t] = 0u; }
    if (t == 0) *done = 0u;
    int lab = label[t];                  // t == k, 256 threads == NN
    int wv = t >> 6;
    #pragma unroll 1
    for (int c = 0; c < 32; ++c) {
      unsigned long long b = __ballot(lab == c);
      if ((t & 63) == 0) cm[c * 4 + wv] = b;
    }
    __syncthreads();
    int n = t;
    unsigned long long pm0 = cm[lab*4+0], pm1 = cm[lab*4+1],
                       pm2 = cm[lab*4+2], pm3 = cm[lab*4+3];
    const unsigned long long P0 = pm0, P1 = pm1, P2 = pm2, P3 = pm3;
    unsigned long long e0 = 0, e1 = 0, e2 = 0, e3 = 0;
    #pragma unroll
    for (int r = 0; r < 8; ++r) {        // first 8 of stable order (pos then neg)
      unsigned long long q0 = pm0, q1 = pm1, q2 = pm2, q3 = pm3;
      if (!(pm0 | pm1 | pm2 | pm3)) {    // P<8 fallback: promote negatives
        q0 = ~(P0 | e0); q1 = ~(P1 | e1); q2 = ~(P2 | e2); q3 = ~(P3 | e3);
      }
      int k;
      if (q0) k = __builtin_ctzll(q0);
      else if (q1) k = 64 + __builtin_ctzll(q1);
      else if (q2) k = 128 + __builtin_ctzll(q2);
      else if (q3) k = 192 + __builtin_ctzll(q3);
      else k = 0;
      pos_idx[n * KPOS + r] = k;
      unsigned long long b = 1ull << (k & 63);
      if (k < 64)       { pm0 &= ~b; e0 |= b; }
      else if (k < 128) { pm1 &= ~b; e1 |= b; }
      else if (k < 192) { pm2 &= ~b; e2 |= b; }
      else              { pm3 &= ~b; e3 |= b; }
    }
    neg_mask[n*4+0] = ~e0; neg_mask[n*4+1] = ~e1;
    neg_mask[n*4+2] = ~e2; neg_mask[n*4+3] = ~e3;
    return;
  }

  int rb = bid >> 6, cb = (bid >> 2) & 15, mq = bid & 3;
  // read phase: 512 (n,c) pairs x 16 m; each thread: 8 float4 loads
  int s = t & 3, pg = t >> 2;
  #pragma unroll
  for (int it = 0; it < 8; ++it) {
    int p = it * 64 + pg;               // 0..511 (p = c_loc*16 + n_loc)
    int n_loc = p & 15, c_loc = p >> 4;
    const float4 v4 = *(const float4*)&f[((size_t)(rb * 16 + n_loc) * CCH
                                          + (cb * 32 + c_loc)) * MMM + mq * 16 + s * 4];
    // column = (s*4+q) ^ (4*lg_w), lg_w = c_loc>>3 = p>>7  (bits 2-3 XOR)
    unsigned int* W = &S[p * 17 + (4 * (s ^ (p >> 7)))];
    W[0] = (unsigned int)__builtin_bit_cast(unsigned short, (_Float16)v4.x);
    W[1] = (unsigned int)__builtin_bit_cast(unsigned short, (_Float16)v4.y);
    W[2] = (unsigned int)__builtin_bit_cast(unsigned short, (_Float16)v4.z);
    W[3] = (unsigned int)__builtin_bit_cast(unsigned short, (_Float16)v4.w);
  }
  __syncthreads();
  // write phase: 16 m_loc x 64 lanes fragments, coalesced 16B stores
  #pragma unroll
  for (int it = 0; it < 4; ++it) {
    int e = it * 256 + t;
    int m_loc = e >> 6, l = e & 63;
    int m = mq * 16 + m_loc;
    int lg = l >> 4;
    int mcol = m_loc ^ (lg << 2);       // same XOR as writer
    f16x8 vh;
    #pragma unroll
    for (int j = 0; j < 8; ++j) {
      unsigned int w = S[((lg * 8 + j) * 16 + (l & 15)) * 17 + mcol];
      vh[j] = __builtin_bit_cast(_Float16, (unsigned short)(w & 0xffffu));
    }
    Ph[FRAG(m, rb, cb) + l] = vh;
  }
}

// ---------------------------------------------------------------------------
// Kernel A2: per (m, class) 8x8 exact distances of the ROUNDED points.
// Self-distance exactly 0 structurally (diag uses the same D8 value twice).
// ---------------------------------------------------------------------------
__global__ __launch_bounds__(256) void kA2(const f16x8* __restrict__ Ph,
                                           const int* __restrict__ pos_idx,
                                           float* __restrict__ x2,
                                           float* __restrict__ dap) {
  __shared__ float R[8][520];
  __shared__ float D8[64];
  int bid = blockIdx.x;
  int m = bid & 63, cl = bid >> 6;
  int t = threadIdx.x;
  #pragma unroll
  for (int half = 0; half < 2; ++half) {
    int e = half * 256 + t;
    int i = e >> 6, le = e & 63, cbb = le >> 2, g = le & 3;
    int mi = pos_idx[cl * 8 + i];
    f16x8 vh = Ph[FRAG(m, mi >> 4, cbb) + (g * 16 + (mi & 15))];
    #pragma unroll
    for (int j = 0; j < 8; ++j)
      R[i][cbb * 32 + g * 8 + j] = (float)vh[j];
  }
  __syncthreads();
  {
    int d = t >> 2, q = t & 3, i = d >> 3, i2 = d & 7;
    const float4* Ri4 = (const float4*)(&R[i][q * 128]);
    const float4* Rj4 = (const float4*)(&R[i2][q * 128]);
    float p = 0.0f;
    #pragma unroll
    for (int c = 0; c < 32; ++c) {
      float4 a = Ri4[c], b = Rj4[c];
      p += a.x * b.x + a.y * b.y + a.z * b.z + a.w * b.w;
    }
    p += __shfl_down(p, 2, 4);
    p += __shfl_down(p, 1, 4);
    if (q == 0) D8[d] = p;
  }
  __syncthreads();
  if (t < 64) {
    int ii = t >> 3, jj = t & 7;
    float x2a = D8[ii * 8 + ii], x2b = D8[jj * 8 + jj];
    float z = x2a + x2b - 2.0f * D8[t];
    float dist = (z > 0.0f) ? sqrtf(z) : 0.0f;
    int mi = pos_idx[cl * 8 + ii];
    dap[((size_t)m * NN + mi) * KPOS + jj] = dist;
    if (ii == jj) x2[m * NN + mi] = x2a;
  }
}

// ---------------------------------------------------------------------------
// Kernel B v7: triangle tiling + 5-buffer depth-3 counted-vmcnt pipeline.
// NB=5 is required for soundness: stage(cb+3) overwrites buffer (cb-2)%5,
// whose reads completed before barrier(cb-1) <= this stage's issue point.
// (r12's NB=3 depth-2 had a one-barrier race that passed by DMA latency.)
// vmcnt(6): 3 stage-pairs in flight; tail peels 4/2/0.
// ---------------------------------------------------------------------------
#define MFMA16(d, a, b) d = __builtin_amdgcn_mfma_f32_16x16x32_f16(a, b, d, 0, 0, 0)

__global__ __launch_bounds__(256) void kB(
    const f16x8* __restrict__ Ph,
    const float* __restrict__ x2, const float* __restrict__ dap,
    const unsigned long long* __restrict__ neg_mask,
    float* __restrict__ s_acc, unsigned int* __restrict__ c_acc,
    unsigned int* __restrict__ done, float* __restrict__ out) {
  __shared__ __align__(16) char Lds[5][8 * 1024];   // 5-deep, 40 KB
  __shared__ float red_s[4];
  __shared__ unsigned int red_c[4];
  __shared__ unsigned int lastFlag;

  int bid = blockIdx.x;                 // 640 blocks
  int m = bid & 63;                     // XCD-aligned: m%8 == bid%8
  int sub = bid >> 6;                   // 0..9 triangle tile id
  int ti, tj;                           // A-side (rows/k) block, B-side (cols/n)
  if (sub < 4) { ti = sub; tj = sub; }
  else {
    int u = sub - 4;                    // (0,1)(0,2)(0,3)(1,2)(1,3)(2,3)
    ti = (u < 3) ? 0 : ((u < 5) ? 1 : 2);
    tj = (u < 3) ? (u + 1) : ((u < 5) ? (u - 2) : 3);
  }
  const bool diag = (ti == tj);
  int t = threadIdx.x, lane = t & 63, w = t >> 6;
  int wr = w & 1, wc = w >> 1;          // wave: 32k x 32n sub-tile

  f32x4 hh[2][2];
  #pragma unroll
  for (int i = 0; i < 2; ++i)
    #pragma unroll
    for (int j = 0; j < 2; ++j) hh[i][j] = (f32x4){0.f, 0.f, 0.f, 0.f};

  // uniform 8 frag-blocks/chunk: b<4 A rows (ti), b>=4 B rows (tj).
  // (diag: tj==ti -> A duplicated into B slots; keeps load count uniform.)
  #define STAGE(nbuf, cbn)                                                   \
    { { int b = w * 2;     int rbg = (b < 4) ? (ti*4 + b) : (tj*4 + b - 4);  \
        GLD_LDS16(Ph + FRAG(m, rbg, (cbn)) + lane, &Lds[nbuf][b * 1024]); }  \
      { int b = w * 2 + 1; int rbg = (b < 4) ? (ti*4 + b) : (tj*4 + b - 4);  \
        GLD_LDS16(Ph + FRAG(m, rbg, (cbn)) + lane, &Lds[nbuf][b * 1024]); } }

  STAGE(0, 0);
  STAGE(1, 1);
  STAGE(2, 2);
  #pragma unroll 1
  for (int cb = 0; cb < 16; ++cb) {
    int buf = cb % 5;
    if (cb < 13) {
      STAGE((cb + 3) % 5, cb + 3);
      asm volatile("s_waitcnt vmcnt(6)" ::: "memory");   // 3 pairs in flight
    } else if (cb == 13) {
      asm volatile("s_waitcnt vmcnt(4)" ::: "memory");
    } else if (cb == 14) {
      asm volatile("s_waitcnt vmcnt(2)" ::: "memory");
    } else {
      asm volatile("s_waitcnt vmcnt(0)" ::: "memory");
    }
    __builtin_amdgcn_s_barrier();       // raw barrier: no vmcnt drain
    __builtin_amdgcn_sched_barrier(0);  // pin reads below the barrier
    const f16x8* L  = (const f16x8*)(Lds[buf]);
    const f16x8* LB = L + 4 * 64;
    f16x8 ah0 = L [(wr * 2 + 0) * 64 + lane];
    f16x8 ah1 = L [(wr * 2 + 1) * 64 + lane];
    f16x8 bh0 = LB[(wc * 2 + 0) * 64 + lane];
    f16x8 bh1 = LB[(wc * 2 + 1) * 64 + lane];
    MFMA16(hh[0][0], ah0, bh0); MFMA16(hh[0][1], ah0, bh1);
    MFMA16(hh[1][0], ah1, bh0); MFMA16(hh[1][1], ah1, bh1);
  }

  // Epilogue. D frag: col = lane&15 (n side), row = (lane>>4)*4 + reg (k side).
  int col = lane & 15, rq = lane >> 4;
  int n0 = tj * 64 + wc * 32 + col;
  int n1 = n0 + 16;
  float x2n0 = x2[m * NN + n0], x2n1 = x2[m * NN + n1];
  float dv0[8], dv1[8];
  {
    const float4* dp0 = (const float4*)&dap[((size_t)m * NN + n0) * KPOS];
    const float4* dp1 = (const float4*)&dap[((size_t)m * NN + n1) * KPOS];
    float4 w0 = dp0[0], w1 = dp0[1], w2 = dp1[0], w3 = dp1[1];
    dv0[0]=w0.x; dv0[1]=w0.y; dv0[2]=w0.z; dv0[3]=w0.w;
    dv0[4]=w1.x; dv0[5]=w1.y; dv0[6]=w1.z; dv0[7]=w1.w;
    dv1[0]=w2.x; dv1[1]=w2.y; dv1[2]=w2.z; dv1[3]=w2.w;
    dv1[4]=w3.x; dv1[5]=w3.y; dv1[6]=w3.z; dv1[7]=w3.w;
  }
  unsigned long long nmw0 = neg_mask[n0 * 4 + ti];   // k word == ti
  unsigned long long nmw1 = neg_mask[n1 * 4 + ti];

  float ls = 0.0f; unsigned int lc = 0u;
  #pragma unroll
  for (int i = 0; i < 2; ++i) {
    #pragma unroll
    for (int reg = 0; reg < 4; ++reg) {
      int klo = wr * 32 + i * 16 + rq * 4 + reg;     // k & 63
      int k = ti * 64 + klo;
      float x2k = x2[m * NN + k];
      float z0 = x2n0 + x2k - 2.0f * hh[i][0][reg];
      float d0 = (z0 > 0.0f) ? sqrtf(z0) : 0.0f;
      float z1 = x2n1 + x2k - 2.0f * hh[i][1][reg];
      float d1 = (z1 > 0.0f) ? sqrtf(z1) : 0.0f;
      // orientation 1: n = cols (n0/n1), k = row
      if ((nmw0 >> klo) & 1ull) {
        #pragma unroll
        for (int p = 0; p < 8; ++p) {
          float tt = MARG + dv0[p] - d0;
          if (tt > 0.0f) { ls += tt; lc++; }
        }
      }
      if ((nmw1 >> klo) & 1ull) {
        #pragma unroll
        for (int p = 0; p < 8; ++p) {
          float tt = MARG + dv1[p] - d1;
          if (tt > 0.0f) { ls += tt; lc++; }
        }
      }
      // orientation 2 (off-diag only): n = row k, negatives = cols n0/n1
      if (!diag) {
        const float4* dpr = (const float4*)&dap[((size_t)m * NN + k) * KPOS];
        float4 q0 = dpr[0], q1 = dpr[1];
        unsigned long long nmr = neg_mask[k * 4 + tj];
        int bit0 = wc * 32 + col;
        if ((nmr >> bit0) & 1ull) {
          float tt;
          tt = MARG + q0.x - d0; if (tt > 0.0f) { ls += tt; lc++; }
          tt = MARG + q0.y - d0; if (tt > 0.0f) { ls += tt; lc++; }
          tt = MARG + q0.z - d0; if (tt > 0.0f) { ls += tt; lc++; }
          tt = MARG + q0.w - d0; if (tt > 0.0f) { ls += tt; lc++; }
          tt = MARG + q1.x - d0; if (tt > 0.0f) { ls += tt; lc++; }
          tt = MARG + q1.y - d0; if (tt > 0.0f) { ls += tt; lc++; }
          tt = MARG + q1.z - d0; if (tt > 0.0f) { ls += tt; lc++; }
          tt = MARG + q1.w - d0; if (tt > 0.0f) { ls += tt; lc++; }
        }
        if ((nmr >> (bit0 + 16)) & 1ull) {
          float tt;
          tt = MARG + q0.x - d1; if (tt > 0.0f) { ls += tt; lc++; }
          tt = MARG + q0.y - d1; if (tt > 0.0f) { ls += tt; lc++; }
          tt = MARG + q0.z - d1; if (tt > 0.0f) { ls += tt; lc++; }
          tt = MARG + q0.w - d1; if (tt > 0.0f) { ls += tt; lc++; }
          tt = MARG + q1.x - d1; if (tt > 0.0f) { ls += tt; lc++; }
          tt = MARG + q1.y - d1; if (tt > 0.0f) { ls += tt; lc++; }
          tt = MARG + q1.z - d1; if (tt > 0.0f) { ls += tt; lc++; }
          tt = MARG + q1.w - d1; if (tt > 0.0f) { ls += tt; lc++; }
        }
      }
    }
  }
  #pragma unroll
  for (int off = 32; off > 0; off >>= 1) {
    ls += __shfl_down(ls, off, 64);
    lc += __shfl_down(lc, off, 64);
  }
  if (lane == 0) { red_s[w] = ls; red_c[w] = lc; }
  __syncthreads();
  if (t == 0) {
    atomicAdd(&s_acc[m], red_s[0] + red_s[1] + red_s[2] + red_s[3]);
    atomicAdd(&c_acc[m], red_c[0] + red_c[1] + red_c[2] + red_c[3]);
    __threadfence();
    unsigned int prev = atomicAdd(done, 1u);
    lastFlag = (prev == 639u) ? 1u : 0u;
  }
  __syncthreads();
  if (lastFlag && t < 64) {             // last block finalizes (fold of kC)
    __threadfence();
    float c  = (float)c_acc[t];
    float sm = s_acc[t];
    float mean = (c > 0.0f) ? (sm / c) : 0.0f;
    float csum = c;
    #pragma unroll
    for (int off = 32; off > 0; off >>= 1) {
      mean += __shfl_down(mean, off, 64);
      csum += __shfl_down(csum, off, 64);
    }
    if (t == 0) {
      out[0] = mean / 64.0f;
      // lm.size = M * N * K * (N-K) = 64*256*8*248 = 32,505,856
      out[1] = (csum / 64.0f) / 32505856.0f;
    }
  }
}

extern "C" void kernel_launch(void* const* d_in, const int* in_sizes, int n_in,
                              void* d_out, int out_size, void* d_ws, size_t ws_size,
                              hipStream_t stream) {
  const float* feature = (const float*)d_in[0];
  const int*   label   = (const int*)d_in[1];
  char* w = (char*)d_ws;
  f16x8* Ph = (f16x8*)(w + PH_OFF);
  float* x2  = (float*)(w + X2_OFF);
  float* dap = (float*)(w + DAP_OFF);
  int*   pos = (int*)(w + POS_OFF);
  unsigned long long* neg = (unsigned long long*)(w + NEG_OFF);
  float* s_acc = (float*)(w + S_OFF);
  unsigned int* c_acc = (unsigned int*)(w + CNT_OFF);
  unsigned int* done  = (unsigned int*)(w + DONE_OFF);
  float* out = (float*)d_out;

  kTH<<<1025, 256, 0, stream>>>(feature, Ph, label, pos, neg, s_acc, c_acc, done);
  kA2<<<2048, 256, 0, stream>>>(Ph, pos, x2, dap);
  kB <<<640,  256, 0, stream>>>(Ph, x2, dap, neg, s_acc, c_acc, done, out);
}

// Round 15
// 46.514 us; speedup vs baseline: 4.0023x; 1.2700x over previous
//
#include <hip/hip_runtime.h>
#include <math.h>

// Problem constants (fixed by setup_inputs)
#define NN   256   // N rows
#define CCH  512   // C features
#define MMM  64    // M slices
#define KPOS 8     // K positives
#define MARG 0.2f

typedef _Float16 f16x8 __attribute__((ext_vector_type(8)));
typedef _Float16 f16x2 __attribute__((ext_vector_type(2)));
typedef float    f32x4 __attribute__((ext_vector_type(4)));

// Packed fragment layout (MFMA A and B operands read the same pattern):
// P[m][rb][cb][lane] : lane l holds X[m][rb*16 + (l&15)][cb*32 + (l>>4)*8 + j]
#define FRAG(m, rb, cb) ((((size_t)(m) * 16 + (rb)) * 16 + (cb)) * 64)

// Workspace layout (bytes).
#define PH_OFF   ((size_t)0)
#define PH_BYTES ((size_t)MMM * 16 * 16 * 64 * 16)   // 16,777,216
#define POS_OFF  (PH_OFF + PH_BYTES)
#define NEG_OFF  (POS_OFF + (size_t)NN * KPOS * 4)
#define S_OFF    (NEG_OFF + (size_t)NN * 4 * 8)
#define CNT_OFF  (S_OFF + (size_t)MMM * 4)
#define DONE_OFF (CNT_OFF + (size_t)MMM * 4)

// async global->LDS, 16B per lane: LDS dest = wave-uniform base + lane*16
#define GLD_LDS16(gp, lp) __builtin_amdgcn_global_load_lds(                 \
    (const __attribute__((address_space(1))) void*)(gp),                    \
    (__attribute__((address_space(3))) void*)(lp), 16, 0, 0)

// fp32 sum of squares of 8 fp16 values, fixed order (deterministic).
static __device__ __forceinline__ float rowsq(f16x8 v, float acc) {
#if __has_builtin(__builtin_amdgcn_fdot2)
  f16x2 p0 = {v[0], v[1]}, p1 = {v[2], v[3]}, p2 = {v[4], v[5]}, p3 = {v[6], v[7]};
  acc = __builtin_amdgcn_fdot2(p0, p0, acc, false);
  acc = __builtin_amdgcn_fdot2(p1, p1, acc, false);
  acc = __builtin_amdgcn_fdot2(p2, p2, acc, false);
  acc = __builtin_amdgcn_fdot2(p3, p3, acc, false);
#else
  #pragma unroll
  for (int e = 0; e < 8; ++e) { float f = (float)v[e]; acc = fmaf(f, f, acc); }
#endif
  return acc;
}

// ---------------------------------------------------------------------------
// Kernel TH: fused transpose + fp16 convert + fragment packing (r13 layout:
// stride 17 + XOR column swizzle, conflict-free). Block 1024 runs the kP
// ballot logic and zeroes accumulators + done counter.
// ---------------------------------------------------------------------------
__global__ __launch_bounds__(256) void kTH(const float* __restrict__ f,
                                           f16x8* __restrict__ Ph,
                                           const int* __restrict__ label,
                                           int* __restrict__ pos_idx,
                                           unsigned long long* __restrict__ neg_mask,
                                           float* __restrict__ s_acc,
                                           unsigned int* __restrict__ c_acc,
                                           unsigned int* __restrict__ done) {
  __shared__ unsigned int S[512 * 17 + 16];   // ~34.9 KB
  int bid = blockIdx.x;
  int t = threadIdx.x;

  if (bid >= 1024) {                     // ---- kP body (ballot version) ----
    unsigned long long* cm = (unsigned long long*)S;   // [32 classes][4 words]
    if (t < MMM) { s_acc[t] = 0.0f; c_acc[t] = 0u; }
    if (t == 0) *done = 0u;
    int lab = label[t];                  // t == k, 256 threads == NN
    int wv = t >> 6;
    #pragma unroll 1
    for (int c = 0; c < 32; ++c) {
      unsigned long long b = __ballot(lab == c);
      if ((t & 63) == 0) cm[c * 4 + wv] = b;
    }
    __syncthreads();
    int n = t;
    unsigned long long pm0 = cm[lab*4+0], pm1 = cm[lab*4+1],
                       pm2 = cm[lab*4+2], pm3 = cm[lab*4+3];
    const unsigned long long P0 = pm0, P1 = pm1, P2 = pm2, P3 = pm3;
    unsigned long long e0 = 0, e1 = 0, e2 = 0, e3 = 0;
    #pragma unroll
    for (int r = 0; r < 8; ++r) {        // first 8 of stable order (pos then neg)
      unsigned long long q0 = pm0, q1 = pm1, q2 = pm2, q3 = pm3;
      if (!(pm0 | pm1 | pm2 | pm3)) {    // P<8 fallback: promote negatives
        q0 = ~(P0 | e0); q1 = ~(P1 | e1); q2 = ~(P2 | e2); q3 = ~(P3 | e3);
      }
      int k;
      if (q0) k = __builtin_ctzll(q0);
      else if (q1) k = 64 + __builtin_ctzll(q1);
      else if (q2) k = 128 + __builtin_ctzll(q2);
      else if (q3) k = 192 + __builtin_ctzll(q3);
      else k = 0;
      pos_idx[n * KPOS + r] = k;
      unsigned long long b = 1ull << (k & 63);
      if (k < 64)       { pm0 &= ~b; e0 |= b; }
      else if (k < 128) { pm1 &= ~b; e1 |= b; }
      else if (k < 192) { pm2 &= ~b; e2 |= b; }
      else              { pm3 &= ~b; e3 |= b; }
    }
    neg_mask[n*4+0] = ~e0; neg_mask[n*4+1] = ~e1;
    neg_mask[n*4+2] = ~e2; neg_mask[n*4+3] = ~e3;
    return;
  }

  int rb = bid >> 6, cb = (bid >> 2) & 15, mq = bid & 3;
  // read phase: 512 (n,c) pairs x 16 m; each thread: 8 float4 loads
  int s = t & 3, pg = t >> 2;
  #pragma unroll
  for (int it = 0; it < 8; ++it) {
    int p = it * 64 + pg;               // 0..511 (p = c_loc*16 + n_loc)
    int n_loc = p & 15, c_loc = p >> 4;
    const float4 v4 = *(const float4*)&f[((size_t)(rb * 16 + n_loc) * CCH
                                          + (cb * 32 + c_loc)) * MMM + mq * 16 + s * 4];
    unsigned int* W = &S[p * 17 + (4 * (s ^ (p >> 7)))];
    W[0] = (unsigned int)__builtin_bit_cast(unsigned short, (_Float16)v4.x);
    W[1] = (unsigned int)__builtin_bit_cast(unsigned short, (_Float16)v4.y);
    W[2] = (unsigned int)__builtin_bit_cast(unsigned short, (_Float16)v4.z);
    W[3] = (unsigned int)__builtin_bit_cast(unsigned short, (_Float16)v4.w);
  }
  __syncthreads();
  // write phase: 16 m_loc x 64 lanes fragments, coalesced 16B stores
  #pragma unroll
  for (int it = 0; it < 4; ++it) {
    int e = it * 256 + t;
    int m_loc = e >> 6, l = e & 63;
    int m = mq * 16 + m_loc;
    int lg = l >> 4;
    int mcol = m_loc ^ (lg << 2);       // same XOR as writer
    f16x8 vh;
    #pragma unroll
    for (int j = 0; j < 8; ++j) {
      unsigned int w = S[((lg * 8 + j) * 16 + (l & 15)) * 17 + mcol];
      vh[j] = __builtin_bit_cast(_Float16, (unsigned short)(w & 0xffffu));
    }
    Ph[FRAG(m, rb, cb) + l] = vh;
  }
}

// ---------------------------------------------------------------------------
// Kernel B2 (2-node design): block = (m, 32-col slice). Stages ALL 256 rows
// chunk-wise (counted-vmcnt pipeline, NB=4 depth-2), computes the 256x32
// column-Gram via MFMA, x2 via in-loop fdot2 on the same A-fragments
// (fixed reduction order -> identical across blocks), exchanges the d_ap
// values through LDS (each (pk,n) entry owned by exactly one lane), then
// the masked triplet loss. Self-distance forced to exact 0. No kA2 node.
// ---------------------------------------------------------------------------
#define MFMA16(d, a, b) d = __builtin_amdgcn_mfma_f32_16x16x32_f16(a, b, d, 0, 0, 0)

__global__ __launch_bounds__(512, 4) void kB2(
    const f16x8* __restrict__ Ph, const int* __restrict__ pos_idx,
    const unsigned long long* __restrict__ neg_mask,
    float* __restrict__ s_acc, unsigned int* __restrict__ c_acc,
    unsigned int* __restrict__ done, float* __restrict__ out) {
  __shared__ __align__(16) char Lds[4][16 * 1024];   // 64 KB ring
  __shared__ float x2s[256];
  __shared__ float dapl[32][8];
  __shared__ float red_s[8];
  __shared__ unsigned int red_c[8];
  __shared__ unsigned int lastFlag;

  int bid = blockIdx.x;                 // 512 blocks
  int m = bid & 63;                     // XCD-aligned: m%8 == bid%8
  int tjj = bid >> 6;                   // 0..7: 32-column slice
  int t = threadIdx.x, lane = t & 63, w = t >> 6;   // 8 waves
  int n0 = tjj * 32;

  f32x4 acc[2][2];                      // [i: k-row16][j: n-col16]
  acc[0][0] = (f32x4){0,0,0,0}; acc[0][1] = (f32x4){0,0,0,0};
  acc[1][0] = (f32x4){0,0,0,0}; acc[1][1] = (f32x4){0,0,0,0};
  float xa0 = 0.0f, xa1 = 0.0f;         // x2 partials for rows 32w+(lane&15), +16

  // chunk = all 256 rows x 32 c = 16 frag-KB; wave w stages fb = 2w, 2w+1.
  #define STAGE2(nbuf, cbn)                                                  \
    { GLD_LDS16(Ph + FRAG(m, w * 2 + 0, (cbn)) + lane,                       \
                &Lds[nbuf][(w * 2 + 0) * 1024]);                             \
      GLD_LDS16(Ph + FRAG(m, w * 2 + 1, (cbn)) + lane,                       \
                &Lds[nbuf][(w * 2 + 1) * 1024]); }

  STAGE2(0, 0);
  STAGE2(1, 1);
  #pragma unroll 1
  for (int cb = 0; cb < 16; ++cb) {
    int buf = cb & 3;
    if (cb < 14) {
      STAGE2((cb + 2) & 3, cb + 2);
      asm volatile("s_waitcnt vmcnt(4)" ::: "memory");   // 2 stage-pairs fly
    } else if (cb == 14) {
      asm volatile("s_waitcnt vmcnt(2)" ::: "memory");
    } else {
      asm volatile("s_waitcnt vmcnt(0)" ::: "memory");
    }
    __builtin_amdgcn_s_barrier();       // raw barrier: no vmcnt drain
    __builtin_amdgcn_sched_barrier(0);  // pin reads below the barrier
    const f16x8* L = (const f16x8*)(Lds[buf]);
    f16x8 A0 = L[(w * 2 + 0) * 64 + lane];      // wave rows 32w..32w+15
    f16x8 A1 = L[(w * 2 + 1) * 64 + lane];      // wave rows 32w+16..
    f16x8 B0 = L[(tjj * 2 + 0) * 64 + lane];    // cols n0..n0+15
    f16x8 B1 = L[(tjj * 2 + 1) * 64 + lane];    // cols n0+16..
    MFMA16(acc[0][0], A0, B0); MFMA16(acc[0][1], A0, B1);
    MFMA16(acc[1][0], A1, B0); MFMA16(acc[1][1], A1, B1);
    xa0 = rowsq(A0, xa0);               // x2 partial, c-slice (lane>>4)*8
    xa1 = rowsq(A1, xa1);
  }

  // x2: butterfly the 4 c-slice partials per row (lanes l, l^16, l^32, l^48)
  {
    float s0 = xa0; s0 += __shfl_xor(s0, 16, 64); s0 += __shfl_xor(s0, 32, 64);
    float s1 = xa1; s1 += __shfl_xor(s1, 16, 64); s1 += __shfl_xor(s1, 32, 64);
    if ((lane >> 4) == 0) {
      x2s[w * 32 + (lane & 15)] = s0;
      x2s[w * 32 + 16 + (lane & 15)] = s1;
    }
  }
  __syncthreads();

  // Pass A: d_ap exchange. Entry (pk, n) lives in wave pk>>5, lane with
  // lane&15 == n&15 and lane>>4 == (pk&15)>>2, at acc[(pk>>4)&1][j][pk&3].
  #pragma unroll
  for (int j = 0; j < 2; ++j) {
    int n = n0 + j * 16 + (lane & 15);
    #pragma unroll
    for (int p = 0; p < 8; ++p) {
      int pk = pos_idx[n * KPOS + p];
      if ((pk >> 5) == w && (lane >> 4) == ((pk >> 2) & 3)) {
        float g = 0.0f;
        int i1 = (pk >> 4) & 1;
        #pragma unroll
        for (int reg = 0; reg < 4; ++reg)
          if ((pk & 3) == reg) g = i1 ? acc[1][j][reg] : acc[0][j][reg];
        float z = x2s[pk] + x2s[n] - 2.0f * g;
        dapl[n - n0][p] = (pk == n) ? 0.0f : ((z > 0.0f) ? sqrtf(z) : 0.0f);
      }
    }
  }
  __syncthreads();

  // Pass B: masked triplet loss over this block's (k = wave rows, n = cols).
  float ls = 0.0f; unsigned int lc = 0u;
  int kw = w >> 1;                      // neg_mask word for k in [32w, 32w+32)
  #pragma unroll
  for (int j = 0; j < 2; ++j) {
    int n = n0 + j * 16 + (lane & 15);
    float x2n = x2s[n];
    unsigned long long nm = neg_mask[n * 4 + kw];
    float dv[8];
    #pragma unroll
    for (int p = 0; p < 8; ++p) dv[p] = dapl[n - n0][p];
    #pragma unroll
    for (int i = 0; i < 2; ++i) {
      #pragma unroll
      for (int reg = 0; reg < 4; ++reg) {
        int k = 32 * w + i * 16 + (lane >> 4) * 4 + reg;
        float z = x2n + x2s[k] - 2.0f * acc[i][j][reg];
        float d = (z > 0.0f) ? sqrtf(z) : 0.0f;
        if ((nm >> (k & 63)) & 1ull) {
          #pragma unroll
          for (int p = 0; p < 8; ++p) {
            float tt = MARG + dv[p] - d;
            if (tt > 0.0f) { ls += tt; lc++; }
          }
        }
      }
    }
  }
  #pragma unroll
  for (int off = 32; off > 0; off >>= 1) {
    ls += __shfl_down(ls, off, 64);
    lc += __shfl_down(lc, off, 64);
  }
  if (lane == 0) { red_s[w] = ls; red_c[w] = lc; }
  __syncthreads();
  if (t == 0) {
    float S = 0.0f; unsigned int C = 0u;
    #pragma unroll
    for (int i = 0; i < 8; ++i) { S += red_s[i]; C += red_c[i]; }
    atomicAdd(&s_acc[m], S);
    atomicAdd(&c_acc[m], C);
    __threadfence();
    unsigned int prev = atomicAdd(done, 1u);
    lastFlag = (prev == 511u) ? 1u : 0u;
  }
  __syncthreads();
  if (lastFlag && t < 64) {             // last block finalizes (fold of kC)
    __threadfence();
    float c  = (float)c_acc[t];
    float sm = s_acc[t];
    float mean = (c > 0.0f) ? (sm / c) : 0.0f;
    float csum = c;
    #pragma unroll
    for (int off = 32; off > 0; off >>= 1) {
      mean += __shfl_down(mean, off, 64);
      csum += __shfl_down(csum, off, 64);
    }
    if (t == 0) {
      out[0] = mean / 64.0f;
      // lm.size = M * N * K * (N-K) = 64*256*8*248 = 32,505,856
      out[1] = (csum / 64.0f) / 32505856.0f;
    }
  }
}

extern "C" void kernel_launch(void* const* d_in, const int* in_sizes, int n_in,
                              void* d_out, int out_size, void* d_ws, size_t ws_size,
                              hipStream_t stream) {
  const float* feature = (const float*)d_in[0];
  const int*   label   = (const int*)d_in[1];
  char* w = (char*)d_ws;
  f16x8* Ph = (f16x8*)(w + PH_OFF);
  int*   pos = (int*)(w + POS_OFF);
  unsigned long long* neg = (unsigned long long*)(w + NEG_OFF);
  float* s_acc = (float*)(w + S_OFF);
  unsigned int* c_acc = (unsigned int*)(w + CNT_OFF);
  unsigned int* done  = (unsigned int*)(w + DONE_OFF);
  float* out = (float*)d_out;

  kTH<<<1025, 256, 0, stream>>>(feature, Ph, label, pos, neg, s_acc, c_acc, done);
  kB2<<<512,  512, 0, stream>>>(Ph, pos, neg, s_acc, c_acc, done, out);
}